// Round 2
// baseline (874.824 us; speedup 1.0000x reference)
//
#include <hip/hip_runtime.h>
#include <math.h>
#include <stdint.h>

#define D_MODEL 2048
#define NHEAD   16
#define DK      128
#define SEQ     2048
#define BATCH   2
#define MROWS   (BATCH * SEQ)   // 4096

typedef __bf16 bf16;
typedef __bf16 bf16x8 __attribute__((ext_vector_type(8)));
typedef __bf16 bf16x4 __attribute__((ext_vector_type(4)));
typedef float  f32x4  __attribute__((ext_vector_type(4)));

__device__ __forceinline__ bf16 f2bf(float f) {
    unsigned u = __builtin_bit_cast(unsigned, f);
    u += 0x7fffu + ((u >> 16) & 1u);   // round-to-nearest-even
    unsigned short h = (unsigned short)(u >> 16);
    return __builtin_bit_cast(bf16, h);
}

#define GLDS16(gp, lp)                                                        \
    __builtin_amdgcn_global_load_lds(                                         \
        (__attribute__((address_space(1))) void*)(uintptr_t)(gp),             \
        (__attribute__((address_space(3))) void*)(lp), 16, 0, 0)

// ---------------- fp32 -> bf16 convert ----------------
__global__ void cvt_f32_bf16(const float* __restrict__ src,
                             bf16* __restrict__ dst, int n4) {
    int i = blockIdx.x * blockDim.x + threadIdx.x;
    if (i < n4) {
        float4 v = ((const float4*)src)[i];
        bf16x4 o;
        o[0] = f2bf(v.x); o[1] = f2bf(v.y); o[2] = f2bf(v.z); o[3] = f2bf(v.w);
        *(bf16x4*)(dst + (size_t)i * 4) = o;
    }
}

// ---------------- GEMM: C = A[M,K] @ B[N,K]^T (bf16 in, fp32 acc) ----------
// EPI: 0 = bf16 row-major, 1 = fp32 row-major, 2 = bf16 V-transposed layout
template <int EPI>
__global__ __launch_bounds__(256)
void gemm_bt(const bf16* __restrict__ A, const bf16* __restrict__ B,
             void* __restrict__ Cv, int M, int N, int K) {
    __shared__ alignas(16) bf16 sA[128 * 32];
    __shared__ alignas(16) bf16 sB[128 * 32];

    const int tid  = threadIdx.x;
    const int lane = tid & 63;
    const int wid  = tid >> 6;
    const int wm   = wid >> 1, wn = wid & 1;
    const int brow = blockIdx.y * 128, bcol = blockIdx.x * 128;
    const int r16  = lane & 15, g = lane >> 4;

    f32x4 acc[4][4] = {};

    const int c0 = tid, c1 = 256 + tid;
    const int rowS0 = c0 >> 2, colS0 = (c0 & 3) * 8;
    const int rowS1 = c1 >> 2, colS1 = (c1 & 3) * 8;

    for (int kt = 0; kt < K; kt += 32) {
        GLDS16(A + (size_t)(brow + rowS0) * K + kt + colS0, &sA[c0 * 8]);
        GLDS16(A + (size_t)(brow + rowS1) * K + kt + colS1, &sA[c1 * 8]);
        GLDS16(B + (size_t)(bcol + rowS0) * K + kt + colS0, &sB[c0 * 8]);
        GLDS16(B + (size_t)(bcol + rowS1) * K + kt + colS1, &sB[c1 * 8]);
        __syncthreads();

        bf16x8 af[4], bfr[4];
#pragma unroll
        for (int m = 0; m < 4; ++m)
            af[m] = *(const bf16x8*)&sA[(wm * 64 + m * 16 + r16) * 32 + g * 8];
#pragma unroll
        for (int n = 0; n < 4; ++n)
            bfr[n] = *(const bf16x8*)&sB[(wn * 64 + n * 16 + r16) * 32 + g * 8];
#pragma unroll
        for (int m = 0; m < 4; ++m)
#pragma unroll
            for (int n = 0; n < 4; ++n)
                acc[m][n] = __builtin_amdgcn_mfma_f32_16x16x32_bf16(
                    af[m], bfr[n], acc[m][n], 0, 0, 0);
        __syncthreads();
    }

#pragma unroll
    for (int m = 0; m < 4; ++m) {
#pragma unroll
        for (int n = 0; n < 4; ++n) {
            const int col  = bcol + wn * 64 + n * 16 + r16;
            const int row0 = brow + wm * 64 + m * 16 + g * 4;
            if constexpr (EPI == 0) {
                bf16* C = (bf16*)Cv;
#pragma unroll
                for (int r = 0; r < 4; ++r)
                    C[(size_t)(row0 + r) * N + col] = f2bf(acc[m][n][r]);
            } else if constexpr (EPI == 1) {
                float* C = (float*)Cv;
#pragma unroll
                for (int r = 0; r < 4; ++r)
                    C[(size_t)(row0 + r) * N + col] = acc[m][n][r];
            } else {
                // V-transpose: row0 = b*2048+s, col = h*128+d
                // dst row = b*2048 + col, dst col = s (4 consecutive)
                bf16* C = (bf16*)Cv;
                const int b = row0 >> 11, s = row0 & 2047;
                bf16x4 v;
#pragma unroll
                for (int r = 0; r < 4; ++r) v[r] = f2bf(acc[m][n][r]);
                *(bf16x4*)&C[(size_t)(b * 2048 + col) * 2048 + s] = v;
            }
        }
    }
}

// ---------------- causal flash attention ----------------
// grid: (S/64 q-tiles, B*H). 4 waves/block, each wave owns 16 q-rows.
__global__ __launch_bounds__(256)
void attn_fwd(const bf16* __restrict__ Q, const bf16* __restrict__ Kb,
              const bf16* __restrict__ Vt, bf16* __restrict__ AO) {
    __shared__ alignas(16) bf16 P_lds[4][16][48];  // padded: 96B row stride

    const int tid  = threadIdx.x;
    const int lane = tid & 63;
    const int wid  = tid >> 6;
    const int r16  = lane & 15, g = lane >> 4;
    const int bh   = blockIdx.y;
    const int b    = bh >> 4;
    const int qbase = blockIdx.x * 64 + wid * 16;
    const size_t rowbase = (size_t)b * SEQ;
    const int hcol = (bh & 15) * DK;
    const float scale = 0.08838834764831845f;  // 1/sqrt(128)

    // Q fragments: 4 chunks of k=32 along d
    bf16x8 aq[4];
    {
        const bf16* qp = Q + (rowbase + qbase + r16) * D_MODEL + hcol + g * 8;
#pragma unroll
        for (int c = 0; c < 4; ++c) aq[c] = *(const bf16x8*)(qp + c * 32);
    }

    f32x4 o[8] = {};
    float m_run[4] = {-INFINITY, -INFINITY, -INFINITY, -INFINITY};
    float l_run[4] = {0.f, 0.f, 0.f, 0.f};

    const int ntile = (qbase + 16 + 31) >> 5;
    for (int t = 0; t < ntile; ++t) {
        const int kv0 = t * 32;
        f32x4 s[2] = {};
#pragma unroll
        for (int hh = 0; hh < 2; ++hh) {
            const bf16* kp =
                Kb + (rowbase + kv0 + hh * 16 + r16) * D_MODEL + hcol + g * 8;
#pragma unroll
            for (int c = 0; c < 4; ++c) {
                bf16x8 bk = *(const bf16x8*)(kp + c * 32);
                s[hh] = __builtin_amdgcn_mfma_f32_16x16x32_bf16(aq[c], bk,
                                                               s[hh], 0, 0, 0);
            }
        }
#pragma unroll
        for (int hh = 0; hh < 2; ++hh)
#pragma unroll
            for (int r = 0; r < 4; ++r) s[hh][r] *= scale;

        if (kv0 + 31 > qbase) {  // causal mask needed
#pragma unroll
            for (int hh = 0; hh < 2; ++hh)
#pragma unroll
                for (int r = 0; r < 4; ++r) {
                    int kvg = kv0 + hh * 16 + r16;
                    int qg  = qbase + g * 4 + r;
                    if (kvg > qg) s[hh][r] = -INFINITY;
                }
        }

        // row max over 16 lanes in group
        float tm[4];
#pragma unroll
        for (int r = 0; r < 4; ++r) tm[r] = fmaxf(s[0][r], s[1][r]);
#pragma unroll
        for (int d = 1; d < 16; d <<= 1)
#pragma unroll
            for (int r = 0; r < 4; ++r)
                tm[r] = fmaxf(tm[r], __shfl_xor(tm[r], d));

        float alpha[4], nm[4];
#pragma unroll
        for (int r = 0; r < 4; ++r) {
            nm[r]    = fmaxf(m_run[r], tm[r]);
            alpha[r] = __expf(m_run[r] - nm[r]);
            m_run[r] = nm[r];
        }
#pragma unroll
        for (int hh = 0; hh < 2; ++hh)
#pragma unroll
            for (int r = 0; r < 4; ++r) s[hh][r] = __expf(s[hh][r] - nm[r]);

        float rs[4];
#pragma unroll
        for (int r = 0; r < 4; ++r) rs[r] = s[0][r] + s[1][r];
#pragma unroll
        for (int d = 1; d < 16; d <<= 1)
#pragma unroll
            for (int r = 0; r < 4; ++r) rs[r] += __shfl_xor(rs[r], d);
#pragma unroll
        for (int r = 0; r < 4; ++r) l_run[r] = l_run[r] * alpha[r] + rs[r];
#pragma unroll
        for (int dt = 0; dt < 8; ++dt)
#pragma unroll
            for (int r = 0; r < 4; ++r) o[dt][r] *= alpha[r];

        // P -> LDS (transpose to A-fragment layout), then PV
#pragma unroll
        for (int hh = 0; hh < 2; ++hh)
#pragma unroll
            for (int r = 0; r < 4; ++r)
                P_lds[wid][g * 4 + r][hh * 16 + r16] = f2bf(s[hh][r]);

        bf16x8 pa = *(const bf16x8*)&P_lds[wid][r16][g * 8];
        const bf16* vp = Vt + ((size_t)bh * DK) * SEQ + kv0 + g * 8;
#pragma unroll
        for (int dt = 0; dt < 8; ++dt) {
            bf16x8 bv = *(const bf16x8*)(vp + (size_t)(dt * 16 + r16) * SEQ);
            o[dt] = __builtin_amdgcn_mfma_f32_16x16x32_bf16(pa, bv, o[dt],
                                                            0, 0, 0);
        }
    }

#pragma unroll
    for (int dt = 0; dt < 8; ++dt)
#pragma unroll
        for (int r = 0; r < 4; ++r) {
            float val = o[dt][r] / l_run[r];
            AO[(rowbase + qbase + g * 4 + r) * D_MODEL + hcol + dt * 16 + r16] =
                f2bf(val);
        }
}

// ---------------- launch ----------------
extern "C" void kernel_launch(void* const* d_in, const int* in_sizes, int n_in,
                              void* d_out, int out_size, void* d_ws,
                              size_t ws_size, hipStream_t stream) {
    const float* X  = (const float*)d_in[0];
    const float* Wq = (const float*)d_in[1];
    const float* Wk = (const float*)d_in[2];
    const float* Wv = (const float*)d_in[3];
    const float* Wo = (const float*)d_in[4];

    bf16* base = (bf16*)d_ws;
    const size_t NX = (size_t)MROWS * D_MODEL;    // 8,388,608
    const size_t NW = (size_t)D_MODEL * D_MODEL;  // 4,194,304
    bf16* Xb  = base;
    bf16* Qb  = Xb + NX;
    bf16* Kbf = Qb + NX;
    bf16* Vt  = Kbf + NX;
    bf16* AOb = Vt + NX;
    bf16* Wqb = AOb + NX;
    bf16* Wkb = Wqb + NW;
    bf16* Wvb = Wkb + NW;
    bf16* Wob = Wvb + NW;

    // converts
    cvt_f32_bf16<<<(int)(NX / 4 / 256), 256, 0, stream>>>(X, Xb, (int)(NX / 4));
    cvt_f32_bf16<<<(int)(NW / 4 / 256), 256, 0, stream>>>(Wq, Wqb, (int)(NW / 4));
    cvt_f32_bf16<<<(int)(NW / 4 / 256), 256, 0, stream>>>(Wk, Wkb, (int)(NW / 4));
    cvt_f32_bf16<<<(int)(NW / 4 / 256), 256, 0, stream>>>(Wv, Wvb, (int)(NW / 4));
    cvt_f32_bf16<<<(int)(NW / 4 / 256), 256, 0, stream>>>(Wo, Wob, (int)(NW / 4));

    dim3 ggrid(D_MODEL / 128, MROWS / 128);  // (16, 32)
    gemm_bt<0><<<ggrid, 256, 0, stream>>>(Xb, Wqb, Qb, MROWS, D_MODEL, D_MODEL);
    gemm_bt<0><<<ggrid, 256, 0, stream>>>(Xb, Wkb, Kbf, MROWS, D_MODEL, D_MODEL);
    gemm_bt<2><<<ggrid, 256, 0, stream>>>(Xb, Wvb, Vt, MROWS, D_MODEL, D_MODEL);

    attn_fwd<<<dim3(SEQ / 64, BATCH * NHEAD), 256, 0, stream>>>(Qb, Kbf, Vt, AOb);

    gemm_bt<1><<<ggrid, 256, 0, stream>>>(AOb, Wob, d_out, MROWS, D_MODEL,
                                          D_MODEL);
}

// Round 3
// 547.417 us; speedup vs baseline: 1.5981x; 1.5981x over previous
//
#include <hip/hip_runtime.h>
#include <math.h>
#include <stdint.h>

#define D_MODEL 2048
#define NHEAD   16
#define DK      128
#define SEQ     2048
#define BATCH   2
#define MROWS   (BATCH * SEQ)   // 4096

typedef __bf16 bf16;
typedef __bf16 bf16x8 __attribute__((ext_vector_type(8)));
typedef __bf16 bf16x4 __attribute__((ext_vector_type(4)));
typedef float  f32x4  __attribute__((ext_vector_type(4)));

__device__ __forceinline__ bf16 f2bf(float f) {
    unsigned u = __builtin_bit_cast(unsigned, f);
    u += 0x7fffu + ((u >> 16) & 1u);   // round-to-nearest-even
    unsigned short h = (unsigned short)(u >> 16);
    return __builtin_bit_cast(bf16, h);
}

#define GLDS16(gp, lp)                                                        \
    __builtin_amdgcn_global_load_lds(                                         \
        (__attribute__((address_space(1))) void*)(uintptr_t)(gp),             \
        (__attribute__((address_space(3))) void*)(lp), 16, 0, 0)

// ---------------- fp32 -> bf16 convert ----------------
__global__ void cvt_f32_bf16(const float* __restrict__ src,
                             bf16* __restrict__ dst, int n4) {
    int i = blockIdx.x * blockDim.x + threadIdx.x;
    if (i < n4) {
        float4 v = ((const float4*)src)[i];
        bf16x4 o;
        o[0] = f2bf(v.x); o[1] = f2bf(v.y); o[2] = f2bf(v.z); o[3] = f2bf(v.w);
        *(bf16x4*)(dst + (size_t)i * 4) = o;
    }
}

// ---------------- GEMM: C = A[M,K] @ B[N,K]^T (bf16 in, fp32 acc) ----------
// EPI: 0 = bf16 row-major, 1 = fp32 row-major, 2 = bf16 V-transposed layout
template <int EPI>
__global__ __launch_bounds__(256)
void gemm_bt(const bf16* __restrict__ A, const bf16* __restrict__ B,
             void* __restrict__ Cv, int M, int N, int K) {
    __shared__ alignas(16) bf16 sA[128 * 32];
    __shared__ alignas(16) bf16 sB[128 * 32];

    const int tid  = threadIdx.x;
    const int lane = tid & 63;
    const int wid  = tid >> 6;
    const int wm   = wid >> 1, wn = wid & 1;
    const int brow = blockIdx.y * 128, bcol = blockIdx.x * 128;
    const int r16  = lane & 15, g = lane >> 4;

    f32x4 acc[4][4] = {};

    const int c0 = tid, c1 = 256 + tid;
    const int rowS0 = c0 >> 2, colS0 = (c0 & 3) * 8;
    const int rowS1 = c1 >> 2, colS1 = (c1 & 3) * 8;

    for (int kt = 0; kt < K; kt += 32) {
        GLDS16(A + (size_t)(brow + rowS0) * K + kt + colS0, &sA[c0 * 8]);
        GLDS16(A + (size_t)(brow + rowS1) * K + kt + colS1, &sA[c1 * 8]);
        GLDS16(B + (size_t)(bcol + rowS0) * K + kt + colS0, &sB[c0 * 8]);
        GLDS16(B + (size_t)(bcol + rowS1) * K + kt + colS1, &sB[c1 * 8]);
        __syncthreads();

        bf16x8 af[4], bfr[4];
#pragma unroll
        for (int m = 0; m < 4; ++m)
            af[m] = *(const bf16x8*)&sA[(wm * 64 + m * 16 + r16) * 32 + g * 8];
#pragma unroll
        for (int n = 0; n < 4; ++n)
            bfr[n] = *(const bf16x8*)&sB[(wn * 64 + n * 16 + r16) * 32 + g * 8];
#pragma unroll
        for (int m = 0; m < 4; ++m)
#pragma unroll
            for (int n = 0; n < 4; ++n)
                acc[m][n] = __builtin_amdgcn_mfma_f32_16x16x32_bf16(
                    af[m], bfr[n], acc[m][n], 0, 0, 0);
        __syncthreads();
    }

#pragma unroll
    for (int m = 0; m < 4; ++m) {
#pragma unroll
        for (int n = 0; n < 4; ++n) {
            const int col  = bcol + wn * 64 + n * 16 + r16;
            const int row0 = brow + wm * 64 + m * 16 + g * 4;
            if constexpr (EPI == 0) {
                bf16* C = (bf16*)Cv;
#pragma unroll
                for (int r = 0; r < 4; ++r)
                    C[(size_t)(row0 + r) * N + col] = f2bf(acc[m][n][r]);
            } else if constexpr (EPI == 1) {
                float* C = (float*)Cv;
#pragma unroll
                for (int r = 0; r < 4; ++r)
                    C[(size_t)(row0 + r) * N + col] = acc[m][n][r];
            } else {
                // V-transpose: row0 = b*2048+s, col = h*128+d
                bf16* C = (bf16*)Cv;
                const int b = row0 >> 11, s = row0 & 2047;
                bf16x4 v;
#pragma unroll
                for (int r = 0; r < 4; ++r) v[r] = f2bf(acc[m][n][r]);
                *(bf16x4*)&C[(size_t)(b * 2048 + col) * 2048 + s] = v;
            }
        }
    }
}

// ---------------- causal flash attention ----------------
// grid: (16 q-tiles of 128 rows, B*H). 4 waves/block; wave owns 32 q-rows.
// qtile remapped so consecutive 256-block dispatch batches pair light+heavy
// tiles on the same CU (causal load balance).
__global__ __launch_bounds__(256)
void attn_fwd(const bf16* __restrict__ Q, const bf16* __restrict__ Kb,
              const bf16* __restrict__ Vt, bf16* __restrict__ AO) {
    __shared__ alignas(16) bf16 P_lds[4][32][40];  // 80B row stride

    const int tid  = threadIdx.x;
    const int lane = tid & 63;
    const int wid  = tid >> 6;
    const int r16  = lane & 15, g = lane >> 4;
    const int bh   = blockIdx.y;
    const int b    = bh >> 4;
    const int NT   = SEQ / 128;  // 16
    const int qt   = (blockIdx.y & 16) ? (NT - 1 - (int)blockIdx.x)
                                       : (int)blockIdx.x;
    const int qbase = qt * 128 + wid * 32;
    const size_t rowbase = (size_t)b * SEQ;
    const int hcol = (bh & 15) * DK;
    const float scale = 0.08838834764831845f;  // 1/sqrt(128)

    // Q fragments: 2 M-frags x 4 chunks of k=32 along d
    bf16x8 aq[2][4];
#pragma unroll
    for (int m = 0; m < 2; ++m) {
        const bf16* qp =
            Q + (rowbase + qbase + m * 16 + r16) * D_MODEL + hcol + g * 8;
#pragma unroll
        for (int c = 0; c < 4; ++c) aq[m][c] = *(const bf16x8*)(qp + c * 32);
    }

    f32x4 o[2][8] = {};
    float m_run[2][4], l_run[2][4];
#pragma unroll
    for (int m = 0; m < 2; ++m)
#pragma unroll
        for (int r = 0; r < 4; ++r) {
            m_run[m][r] = -INFINITY;
            l_run[m][r] = 0.f;
        }

    const int ntile = (qbase >> 5) + 1;
    for (int t = 0; t < ntile; ++t) {
        const int kv0 = t * 32;
        f32x4 s[2][2] = {};
#pragma unroll
        for (int n = 0; n < 2; ++n) {
            const bf16* kp =
                Kb + (rowbase + kv0 + n * 16 + r16) * D_MODEL + hcol + g * 8;
#pragma unroll
            for (int c = 0; c < 4; ++c) {
                bf16x8 bk = *(const bf16x8*)(kp + c * 32);
#pragma unroll
                for (int m = 0; m < 2; ++m)
                    s[m][n] = __builtin_amdgcn_mfma_f32_16x16x32_bf16(
                        aq[m][c], bk, s[m][n], 0, 0, 0);
            }
        }
#pragma unroll
        for (int m = 0; m < 2; ++m)
#pragma unroll
            for (int n = 0; n < 2; ++n)
#pragma unroll
                for (int r = 0; r < 4; ++r) s[m][n][r] *= scale;

        if (kv0 + 31 > qbase) {  // only the diagonal tile
#pragma unroll
            for (int m = 0; m < 2; ++m)
#pragma unroll
                for (int n = 0; n < 2; ++n)
#pragma unroll
                    for (int r = 0; r < 4; ++r) {
                        int kvg = kv0 + n * 16 + r16;
                        int qg  = qbase + m * 16 + g * 4 + r;
                        if (kvg > qg) s[m][n][r] = -INFINITY;
                    }
        }

        // row max over the 16-lane k groups
        float tm[2][4];
#pragma unroll
        for (int m = 0; m < 2; ++m)
#pragma unroll
            for (int r = 0; r < 4; ++r) tm[m][r] = fmaxf(s[m][0][r], s[m][1][r]);
#pragma unroll
        for (int d = 1; d < 16; d <<= 1)
#pragma unroll
            for (int m = 0; m < 2; ++m)
#pragma unroll
                for (int r = 0; r < 4; ++r)
                    tm[m][r] = fmaxf(tm[m][r], __shfl_xor(tm[m][r], d));

        float alpha[2][4];
#pragma unroll
        for (int m = 0; m < 2; ++m)
#pragma unroll
            for (int r = 0; r < 4; ++r) {
                float nm    = fmaxf(m_run[m][r], tm[m][r]);
                alpha[m][r] = __expf(m_run[m][r] - nm);
                m_run[m][r] = nm;
            }
#pragma unroll
        for (int m = 0; m < 2; ++m)
#pragma unroll
            for (int n = 0; n < 2; ++n)
#pragma unroll
                for (int r = 0; r < 4; ++r)
                    s[m][n][r] = __expf(s[m][n][r] - m_run[m][r]);

        float rs[2][4];
#pragma unroll
        for (int m = 0; m < 2; ++m)
#pragma unroll
            for (int r = 0; r < 4; ++r) rs[m][r] = s[m][0][r] + s[m][1][r];
#pragma unroll
        for (int d = 1; d < 16; d <<= 1)
#pragma unroll
            for (int m = 0; m < 2; ++m)
#pragma unroll
                for (int r = 0; r < 4; ++r) rs[m][r] += __shfl_xor(rs[m][r], d);
#pragma unroll
        for (int m = 0; m < 2; ++m)
#pragma unroll
            for (int r = 0; r < 4; ++r)
                l_run[m][r] = l_run[m][r] * alpha[m][r] + rs[m][r];
#pragma unroll
        for (int m = 0; m < 2; ++m)
#pragma unroll
            for (int dt = 0; dt < 8; ++dt)
#pragma unroll
                for (int r = 0; r < 4; ++r) o[m][dt][r] *= alpha[m][r];

        // P -> LDS (transpose to A-fragment layout), then PV
#pragma unroll
        for (int m = 0; m < 2; ++m)
#pragma unroll
            for (int n = 0; n < 2; ++n)
#pragma unroll
                for (int r = 0; r < 4; ++r)
                    P_lds[wid][m * 16 + g * 4 + r][n * 16 + r16] =
                        f2bf(s[m][n][r]);

        bf16x8 pa[2];
#pragma unroll
        for (int m = 0; m < 2; ++m)
            pa[m] = *(const bf16x8*)&P_lds[wid][m * 16 + r16][g * 8];

        const bf16* vp = Vt + ((size_t)bh * DK) * SEQ + kv0 + g * 8;
#pragma unroll
        for (int dt = 0; dt < 8; ++dt) {
            bf16x8 bv = *(const bf16x8*)(vp + (size_t)(dt * 16 + r16) * SEQ);
#pragma unroll
            for (int m = 0; m < 2; ++m)
                o[m][dt] = __builtin_amdgcn_mfma_f32_16x16x32_bf16(
                    pa[m], bv, o[m][dt], 0, 0, 0);
        }
    }

#pragma unroll
    for (int m = 0; m < 2; ++m) {
        float rl[4];
#pragma unroll
        for (int r = 0; r < 4; ++r) rl[r] = 1.f / l_run[m][r];
#pragma unroll
        for (int dt = 0; dt < 8; ++dt)
#pragma unroll
            for (int r = 0; r < 4; ++r) {
                float val = o[m][dt][r] * rl[r];
                AO[(rowbase + qbase + m * 16 + g * 4 + r) * D_MODEL + hcol +
                   dt * 16 + r16] = f2bf(val);
            }
    }
}

// ---------------- launch ----------------
extern "C" void kernel_launch(void* const* d_in, const int* in_sizes, int n_in,
                              void* d_out, int out_size, void* d_ws,
                              size_t ws_size, hipStream_t stream) {
    const float* X  = (const float*)d_in[0];
    const float* Wq = (const float*)d_in[1];
    const float* Wk = (const float*)d_in[2];
    const float* Wv = (const float*)d_in[3];
    const float* Wo = (const float*)d_in[4];

    bf16* base = (bf16*)d_ws;
    const size_t NX = (size_t)MROWS * D_MODEL;    // 8,388,608
    const size_t NW = (size_t)D_MODEL * D_MODEL;  // 4,194,304
    bf16* Xb  = base;
    bf16* Qb  = Xb + NX;
    bf16* Kbf = Qb + NX;
    bf16* Vt  = Kbf + NX;
    bf16* AOb = Vt + NX;
    bf16* Wqb = AOb + NX;
    bf16* Wkb = Wqb + NW;
    bf16* Wvb = Wkb + NW;
    bf16* Wob = Wvb + NW;

    cvt_f32_bf16<<<(int)(NX / 4 / 256), 256, 0, stream>>>(X, Xb, (int)(NX / 4));
    cvt_f32_bf16<<<(int)(NW / 4 / 256), 256, 0, stream>>>(Wq, Wqb, (int)(NW / 4));
    cvt_f32_bf16<<<(int)(NW / 4 / 256), 256, 0, stream>>>(Wk, Wkb, (int)(NW / 4));
    cvt_f32_bf16<<<(int)(NW / 4 / 256), 256, 0, stream>>>(Wv, Wvb, (int)(NW / 4));
    cvt_f32_bf16<<<(int)(NW / 4 / 256), 256, 0, stream>>>(Wo, Wob, (int)(NW / 4));

    dim3 ggrid(D_MODEL / 128, MROWS / 128);  // (16, 32)
    gemm_bt<0><<<ggrid, 256, 0, stream>>>(Xb, Wqb, Qb, MROWS, D_MODEL, D_MODEL);
    gemm_bt<0><<<ggrid, 256, 0, stream>>>(Xb, Wkb, Kbf, MROWS, D_MODEL, D_MODEL);
    gemm_bt<2><<<ggrid, 256, 0, stream>>>(Xb, Wvb, Vt, MROWS, D_MODEL, D_MODEL);

    attn_fwd<<<dim3(SEQ / 128, BATCH * NHEAD), 256, 0, stream>>>(Qb, Kbf, Vt,
                                                                 AOb);

    gemm_bt<1><<<ggrid, 256, 0, stream>>>(AOb, Wob, d_out, MROWS, D_MODEL,
                                          D_MODEL);
}

// Round 5
// 531.874 us; speedup vs baseline: 1.6448x; 1.0292x over previous
//
#include <hip/hip_runtime.h>
#include <math.h>
#include <stdint.h>

#define D_MODEL 2048
#define NHEAD   16
#define DK      128
#define SEQ     2048
#define BATCH   2
#define MROWS   (BATCH * SEQ)   // 4096

typedef __bf16 bf16;
typedef __bf16 bf16x8 __attribute__((ext_vector_type(8)));
typedef __bf16 bf16x4 __attribute__((ext_vector_type(4)));
typedef float  f32x4  __attribute__((ext_vector_type(4)));

__device__ __forceinline__ bf16 f2bf(float f) {
    unsigned u = __builtin_bit_cast(unsigned, f);
    u += 0x7fffu + ((u >> 16) & 1u);   // round-to-nearest-even
    unsigned short h = (unsigned short)(u >> 16);
    return __builtin_bit_cast(bf16, h);
}

#define GLDS16(gp, lp)                                                        \
    __builtin_amdgcn_global_load_lds(                                         \
        (__attribute__((address_space(1))) void*)(uintptr_t)(gp),             \
        (__attribute__((address_space(3))) void*)(lp), 16, 0, 0)

#define QSCALE 0.08838834764831845f  // 1/sqrt(128)

// ---------------- fp32 -> bf16 convert ----------------
__global__ void cvt_f32_bf16(const float* __restrict__ src,
                             bf16* __restrict__ dst, int n4) {
    int i = blockIdx.x * blockDim.x + threadIdx.x;
    if (i < n4) {
        float4 v = ((const float4*)src)[i];
        bf16x4 o;
        o[0] = f2bf(v.x); o[1] = f2bf(v.y); o[2] = f2bf(v.z); o[3] = f2bf(v.w);
        *(bf16x4*)(dst + (size_t)i * 4) = o;
    }
}

// ---------------- fused QKV GEMM ----------------
// C = X[4096,2048] @ Wqkv[6144,2048]^T.  Per-block epilogue:
//   cols [0,2048)    -> Qb  (bf16, scaled by QSCALE)
//   cols [2048,4096) -> Kbf (bf16)
//   cols [4096,6144) -> Vt  (bf16, transposed per (b,h): Vt[(b*16+h)*128+d][s])
__global__ __launch_bounds__(256)
void gemm_qkv(const bf16* __restrict__ A, const bf16* __restrict__ B,
              bf16* __restrict__ Qb, bf16* __restrict__ Kbf,
              bf16* __restrict__ Vt) {
    __shared__ alignas(16) bf16 sA[128 * 32];
    __shared__ alignas(16) bf16 sB[128 * 32];
    const int K = D_MODEL;

    const int tid  = threadIdx.x;
    const int lane = tid & 63;
    const int wid  = tid >> 6;
    const int wm   = wid >> 1, wn = wid & 1;
    const int brow = blockIdx.y * 128, bcol = blockIdx.x * 128;
    const int r16  = lane & 15, g = lane >> 4;

    f32x4 acc[4][4] = {};

    const int c0 = tid, c1 = 256 + tid;
    const int rowS0 = c0 >> 2, colS0 = (c0 & 3) * 8;
    const int rowS1 = c1 >> 2, colS1 = (c1 & 3) * 8;

    for (int kt = 0; kt < K; kt += 32) {
        GLDS16(A + (size_t)(brow + rowS0) * K + kt + colS0, &sA[c0 * 8]);
        GLDS16(A + (size_t)(brow + rowS1) * K + kt + colS1, &sA[c1 * 8]);
        GLDS16(B + (size_t)(bcol + rowS0) * K + kt + colS0, &sB[c0 * 8]);
        GLDS16(B + (size_t)(bcol + rowS1) * K + kt + colS1, &sB[c1 * 8]);
        __syncthreads();

        bf16x8 af[4], bfr[4];
#pragma unroll
        for (int m = 0; m < 4; ++m)
            af[m] = *(const bf16x8*)&sA[(wm * 64 + m * 16 + r16) * 32 + g * 8];
#pragma unroll
        for (int n = 0; n < 4; ++n)
            bfr[n] = *(const bf16x8*)&sB[(wn * 64 + n * 16 + r16) * 32 + g * 8];
#pragma unroll
        for (int m = 0; m < 4; ++m)
#pragma unroll
            for (int n = 0; n < 4; ++n)
                acc[m][n] = __builtin_amdgcn_mfma_f32_16x16x32_bf16(
                    af[m], bfr[n], acc[m][n], 0, 0, 0);
        __syncthreads();
    }

    const int which = bcol >> 11;  // 0=Q, 1=K, 2=V (tiles never straddle)
#pragma unroll
    for (int m = 0; m < 4; ++m) {
#pragma unroll
        for (int n = 0; n < 4; ++n) {
            const int col  = bcol + wn * 64 + n * 16 + r16;
            const int row0 = brow + wm * 64 + m * 16 + g * 4;
            if (which == 0) {
#pragma unroll
                for (int r = 0; r < 4; ++r)
                    Qb[(size_t)(row0 + r) * D_MODEL + col] =
                        f2bf(acc[m][n][r] * QSCALE);
            } else if (which == 1) {
#pragma unroll
                for (int r = 0; r < 4; ++r)
                    Kbf[(size_t)(row0 + r) * D_MODEL + (col - 2048)] =
                        f2bf(acc[m][n][r]);
            } else {
                const int b = row0 >> 11, s = row0 & 2047;
                bf16x4 v;
#pragma unroll
                for (int r = 0; r < 4; ++r) v[r] = f2bf(acc[m][n][r]);
                *(bf16x4*)&Vt[(size_t)(b * 2048 + (col - 4096)) * 2048 + s] = v;
            }
        }
    }
}

// ---------------- O-projection GEMM (bf16 in, fp32 out) ----------------
__global__ __launch_bounds__(256)
void gemm_o(const bf16* __restrict__ A, const bf16* __restrict__ B,
            float* __restrict__ C) {
    __shared__ alignas(16) bf16 sA[128 * 32];
    __shared__ alignas(16) bf16 sB[128 * 32];
    const int K = D_MODEL, N = D_MODEL;

    const int tid  = threadIdx.x;
    const int lane = tid & 63;
    const int wid  = tid >> 6;
    const int wm   = wid >> 1, wn = wid & 1;
    const int brow = blockIdx.y * 128, bcol = blockIdx.x * 128;
    const int r16  = lane & 15, g = lane >> 4;

    f32x4 acc[4][4] = {};

    const int c0 = tid, c1 = 256 + tid;
    const int rowS0 = c0 >> 2, colS0 = (c0 & 3) * 8;
    const int rowS1 = c1 >> 2, colS1 = (c1 & 3) * 8;

    for (int kt = 0; kt < K; kt += 32) {
        GLDS16(A + (size_t)(brow + rowS0) * K + kt + colS0, &sA[c0 * 8]);
        GLDS16(A + (size_t)(brow + rowS1) * K + kt + colS1, &sA[c1 * 8]);
        GLDS16(B + (size_t)(bcol + rowS0) * K + kt + colS0, &sB[c0 * 8]);
        GLDS16(B + (size_t)(bcol + rowS1) * K + kt + colS1, &sB[c1 * 8]);
        __syncthreads();

        bf16x8 af[4], bfr[4];
#pragma unroll
        for (int m = 0; m < 4; ++m)
            af[m] = *(const bf16x8*)&sA[(wm * 64 + m * 16 + r16) * 32 + g * 8];
#pragma unroll
        for (int n = 0; n < 4; ++n)
            bfr[n] = *(const bf16x8*)&sB[(wn * 64 + n * 16 + r16) * 32 + g * 8];
#pragma unroll
        for (int m = 0; m < 4; ++m)
#pragma unroll
            for (int n = 0; n < 4; ++n)
                acc[m][n] = __builtin_amdgcn_mfma_f32_16x16x32_bf16(
                    af[m], bfr[n], acc[m][n], 0, 0, 0);
        __syncthreads();
    }

#pragma unroll
    for (int m = 0; m < 4; ++m)
#pragma unroll
        for (int n = 0; n < 4; ++n) {
            const int col  = bcol + wn * 64 + n * 16 + r16;
            const int row0 = brow + wm * 64 + m * 16 + g * 4;
#pragma unroll
            for (int r = 0; r < 4; ++r)
                C[(size_t)(row0 + r) * N + col] = acc[m][n][r];
        }
}

// ---------------- causal flash attention ----------------
// grid (16, 32): 128 q-rows/block, 4 waves x 32 rows. KVBLK=64.
// K tile staged in LDS (XOR-swizzled via pre-swizzled global source),
// double-buffered, shared by all 4 waves; 2-phase pipeline (stage t+1
// before compute of t, one __syncthreads per tile).
__global__ __launch_bounds__(256, 2)
void attn_fwd(const bf16* __restrict__ Q, const bf16* __restrict__ Kb,
              const bf16* __restrict__ Vt, bf16* __restrict__ AO) {
    __shared__ alignas(16) bf16 sK[2][64 * 128];   // 2 x 16 KB
    __shared__ alignas(16) bf16 P_lds[4][32][72];  // 144B row stride

    const int tid  = threadIdx.x;
    const int lane = tid & 63;
    const int wid  = tid >> 6;
    const int r16  = lane & 15, g = lane >> 4;
    const int bh   = blockIdx.y;
    const int b    = bh >> 4;
    const int qt   = (blockIdx.y & 16) ? (15 - (int)blockIdx.x)
                                       : (int)blockIdx.x;
    const int qbase = qt * 128 + wid * 32;
    const size_t rowbase = (size_t)b * SEQ;
    const int hcol = (bh & 15) * DK;
    const int nt   = 2 * qt + 2;  // kv tiles of 64 covering [0, qt*128+128)

    // Q fragments (pre-scaled by QSCALE in gemm_qkv epilogue)
    bf16x8 aq[2][4];
#pragma unroll
    for (int m = 0; m < 2; ++m) {
        const bf16* qp =
            Q + (rowbase + qbase + m * 16 + r16) * D_MODEL + hcol + g * 8;
#pragma unroll
        for (int c = 0; c < 4; ++c) aq[m][c] = *(const bf16x8*)(qp + c * 32);
    }

    f32x4 o[2][8] = {};
    float m_run[2][4], l_run[2][4];
#pragma unroll
    for (int m = 0; m < 2; ++m)
#pragma unroll
        for (int r = 0; r < 4; ++r) {
            m_run[m][r] = -3.0e38f;
            l_run[m][r] = 0.f;
        }

    // stage kv-tile t into sK[buf]; 16 GLDS16 issues (4 per wave).
    // LDS dest linear; source column pre-swizzled: colB ^= (row&7)<<4.
    auto stage = [&](int buf, int t) {
        const int kv0 = t * 64;
#pragma unroll
        for (int j = 0; j < 4; ++j) {
            const int ldsOff = wid * 1024 + j * 4096 + lane * 16;  // bytes
            const int row    = ldsOff >> 8;                        // 0..63
            const int colB   = (lane & 15) * 16;
            const int scolB  = colB ^ ((row & 7) << 4);
            const bf16* gp =
                Kb + (rowbase + kv0 + row) * D_MODEL + hcol + (scolB >> 1);
            GLDS16(gp, (bf16*)sK[buf] + (ldsOff >> 1));
        }
    };

    int cur = 0;
    stage(0, 0);
    __syncthreads();

    for (int t = 0; t < nt; ++t) {
        if (t + 1 < nt) stage(cur ^ 1, t + 1);
        const int kv0 = t * 64;

        if (kv0 <= qbase + 31) {  // wave has unmasked work in this tile
            // ---- QK^T ----
            f32x4 s[2][4] = {};
#pragma unroll
            for (int c = 0; c < 4; ++c) {
                bf16x8 kf[4];
#pragma unroll
                for (int n = 0; n < 4; ++n) {
                    const int row  = n * 16 + r16;
                    const int colB = (c * 64 + g * 16) ^ ((row & 7) << 4);
                    kf[n] = *(const bf16x8*)&sK[cur][row * 128 + (colB >> 1)];
                }
#pragma unroll
                for (int n = 0; n < 4; ++n)
#pragma unroll
                    for (int m = 0; m < 2; ++m)
                        s[m][n] = __builtin_amdgcn_mfma_f32_16x16x32_bf16(
                            aq[m][c], kf[n], s[m][n], 0, 0, 0);
            }

            // ---- causal mask (diagonal tiles only) ----
            if (kv0 + 63 > qbase) {
#pragma unroll
                for (int m = 0; m < 2; ++m)
#pragma unroll
                    for (int n = 0; n < 4; ++n)
#pragma unroll
                        for (int r = 0; r < 4; ++r) {
                            int kvg = kv0 + n * 16 + r16;
                            int qg  = qbase + m * 16 + g * 4 + r;
                            if (kvg > qg) s[m][n][r] = -3.0e38f;
                        }
            }

            // ---- online softmax ----
            float tm[2][4];
#pragma unroll
            for (int m = 0; m < 2; ++m)
#pragma unroll
                for (int r = 0; r < 4; ++r)
                    tm[m][r] = fmaxf(fmaxf(s[m][0][r], s[m][1][r]),
                                     fmaxf(s[m][2][r], s[m][3][r]));
#pragma unroll
            for (int d = 1; d < 16; d <<= 1)
#pragma unroll
                for (int m = 0; m < 2; ++m)
#pragma unroll
                    for (int r = 0; r < 4; ++r)
                        tm[m][r] = fmaxf(tm[m][r], __shfl_xor(tm[m][r], d));

            float alpha[2][4];
#pragma unroll
            for (int m = 0; m < 2; ++m)
#pragma unroll
                for (int r = 0; r < 4; ++r) {
                    float nm    = fmaxf(m_run[m][r], tm[m][r]);
                    alpha[m][r] = __expf(m_run[m][r] - nm);
                    m_run[m][r] = nm;
                }
#pragma unroll
            for (int m = 0; m < 2; ++m)
#pragma unroll
                for (int n = 0; n < 4; ++n)
#pragma unroll
                    for (int r = 0; r < 4; ++r)
                        s[m][n][r] = __expf(s[m][n][r] - m_run[m][r]);

            float rs[2][4];
#pragma unroll
            for (int m = 0; m < 2; ++m)
#pragma unroll
                for (int r = 0; r < 4; ++r)
                    rs[m][r] = (s[m][0][r] + s[m][1][r]) +
                               (s[m][2][r] + s[m][3][r]);
#pragma unroll
            for (int d = 1; d < 16; d <<= 1)
#pragma unroll
                for (int m = 0; m < 2; ++m)
#pragma unroll
                    for (int r = 0; r < 4; ++r)
                        rs[m][r] += __shfl_xor(rs[m][r], d);
#pragma unroll
            for (int m = 0; m < 2; ++m)
#pragma unroll
                for (int r = 0; r < 4; ++r)
                    l_run[m][r] = l_run[m][r] * alpha[m][r] + rs[m][r];
#pragma unroll
            for (int m = 0; m < 2; ++m)
#pragma unroll
                for (int dt = 0; dt < 8; ++dt)
#pragma unroll
                    for (int r = 0; r < 4; ++r) o[m][dt][r] *= alpha[m][r];

            // ---- P -> LDS (transpose to A-frag layout) ----
#pragma unroll
            for (int m = 0; m < 2; ++m)
#pragma unroll
                for (int n = 0; n < 4; ++n)
#pragma unroll
                    for (int r = 0; r < 4; ++r)
                        P_lds[wid][m * 16 + g * 4 + r][n * 16 + r16] =
                            f2bf(s[m][n][r]);

            bf16x8 pa[2][2];
#pragma unroll
            for (int m = 0; m < 2; ++m)
#pragma unroll
                for (int c = 0; c < 2; ++c)
                    pa[m][c] = *(const bf16x8*)&P_lds[wid][m * 16 + r16]
                                                    [c * 32 + g * 8];

            // ---- PV ----
            const bf16* vp = Vt + ((size_t)bh * DK) * SEQ + kv0 + g * 8;
#pragma unroll
            for (int dt = 0; dt < 8; ++dt) {
                bf16x8 bv[2];
#pragma unroll
                for (int c = 0; c < 2; ++c)
                    bv[c] = *(const bf16x8*)(vp +
                                             (size_t)(dt * 16 + r16) * SEQ +
                                             c * 32);
#pragma unroll
                for (int m = 0; m < 2; ++m)
#pragma unroll
                    for (int c = 0; c < 2; ++c)
                        o[m][dt] = __builtin_amdgcn_mfma_f32_16x16x32_bf16(
                            pa[m][c], bv[c], o[m][dt], 0, 0, 0);
            }
        }

        __syncthreads();
        cur ^= 1;
    }

#pragma unroll
    for (int m = 0; m < 2; ++m) {
        float rl[4];
#pragma unroll
        for (int r = 0; r < 4; ++r) rl[r] = 1.f / l_run[m][r];
#pragma unroll
        for (int dt = 0; dt < 8; ++dt)
#pragma unroll
            for (int r = 0; r < 4; ++r) {
                float val = o[m][dt][r] * rl[r];
                AO[(rowbase + qbase + m * 16 + g * 4 + r) * D_MODEL + hcol +
                   dt * 16 + r16] = f2bf(val);
            }
    }
}

// ---------------- launch ----------------
extern "C" void kernel_launch(void* const* d_in, const int* in_sizes, int n_in,
                              void* d_out, int out_size, void* d_ws,
                              size_t ws_size, hipStream_t stream) {
    const float* X  = (const float*)d_in[0];
    const float* Wq = (const float*)d_in[1];
    const float* Wk = (const float*)d_in[2];
    const float* Wv = (const float*)d_in[3];
    const float* Wo = (const float*)d_in[4];

    bf16* base = (bf16*)d_ws;
    const size_t NX = (size_t)MROWS * D_MODEL;    // 8,388,608
    const size_t NW = (size_t)D_MODEL * D_MODEL;  // 4,194,304
    bf16* Xb  = base;
    bf16* Qb  = Xb + NX;
    bf16* Kbf = Qb + NX;
    bf16* Vt  = Kbf + NX;
    bf16* AOb = Vt + NX;
    bf16* Wqb = AOb + NX;   // Wq, Wk, Wv contiguous -> fused B [6144, 2048]
    bf16* Wkb = Wqb + NW;
    bf16* Wvb = Wkb + NW;
    bf16* Wob = Wvb + NW;

    cvt_f32_bf16<<<(int)(NX / 4 / 256), 256, 0, stream>>>(X, Xb, (int)(NX / 4));
    cvt_f32_bf16<<<(int)(NW / 4 / 256), 256, 0, stream>>>(Wq, Wqb, (int)(NW / 4));
    cvt_f32_bf16<<<(int)(NW / 4 / 256), 256, 0, stream>>>(Wk, Wkb, (int)(NW / 4));
    cvt_f32_bf16<<<(int)(NW / 4 / 256), 256, 0, stream>>>(Wv, Wvb, (int)(NW / 4));
    cvt_f32_bf16<<<(int)(NW / 4 / 256), 256, 0, stream>>>(Wo, Wob, (int)(NW / 4));

    // fused QKV projection: grid (6144/128, 4096/128) = (48, 32)
    gemm_qkv<<<dim3(48, 32), 256, 0, stream>>>(Xb, Wqb, Qb, Kbf, Vt);

    attn_fwd<<<dim3(SEQ / 128, BATCH * NHEAD), 256, 0, stream>>>(Qb, Kbf, Vt,
                                                                 AOb);

    gemm_o<<<dim3(16, 32), 256, 0, stream>>>(AOb, Wob, (float*)d_out);
}